// Round 6
// baseline (15712.848 us; speedup 1.0000x reference)
//
#include <hip/hip_runtime.h>
#include <hip/hip_bf16.h>

// EncoderBiLSTMMaxPool — round 11: all-gates-local 256-thread recurrence inside the round-10 pipe.
// Insight: the old 512-thr recur step was LDS-ISSUE-bound: 8 waves x (32 h-broadcast + 16 weight)
// ds_read_b128 = 384 DS instr/step ~= 2900 cyc, matching the 3715-cyc step. New engine:
//   256 threads (4 waves, 1 wave/SIMD via ~99KB LDS -> 1 block/CU -> 512 unified regs/wave).
//   Thread j owns unit j with ALL FOUR gates: 104 int4 weights in regs (AGPR-spill path, proven
//   in round 5) + 24 int4 in LDS. h-broadcast DS instrs halve; activation is lane-local ->
//   NO plds exchange, ONE barrier/step (was 2). Same per-gate FP order -> same absmax.
// Workers: 256-thr 128x128 GEMM tiles, 16 per sample (flag1 target 16), round-robin across
// streams so no stream starves. Pipe/sync structure otherwise identical to round 10.

typedef _Float16 f16;
typedef _Float16 h2_t  __attribute__((ext_vector_type(2)));
typedef _Float16 f16x8 __attribute__((ext_vector_type(8)));
typedef float    f32x4 __attribute__((ext_vector_type(4)));

#define B_  128
#define S_  128
#define H_  512
#define HH_ 256
#define M_  (B_ * S_)   // 16384
#define NG  1024        // gates per direction (4*HH)
#define K0  512         // LSTM input dim

#define WS_BASE 106971200u
#define WS_PIPE 106972224u   // + 256 ints of flags

__device__ __forceinline__ float sigmoidf_(float x) { return 1.0f / (1.0f + __expf(-x)); }
__device__ __forceinline__ float tanhf_(float x)    { return 1.0f - 2.0f / (__expf(2.0f * x) + 1.0f); }

__device__ __forceinline__ float ldf(const void* p, long i, int isbf) {
    return isbf ? __bfloat162float(((const __hip_bfloat16*)p)[i]) : ((const float*)p)[i];
}

__device__ __forceinline__ float dot2f(int w, int h, float acc) {
#if __has_builtin(__builtin_amdgcn_fdot2)
    return __builtin_amdgcn_fdot2(__builtin_bit_cast(h2_t, w), __builtin_bit_cast(h2_t, h), acc, false);
#else
    h2_t a = __builtin_bit_cast(h2_t, w), b = __builtin_bit_cast(h2_t, h);
    return acc + (float)a[0] * (float)b[0] + (float)a[1] * (float)b[1];
#endif
}

// ---- sync helpers: single-thread poll / single-thread release ----
template <int SLP>
__device__ __forceinline__ void block_wait_ge(int* p, int v) {
    if (threadIdx.x == 0) {
        while (__hip_atomic_load(p, __ATOMIC_RELAXED, __HIP_MEMORY_SCOPE_AGENT) < v)
            __builtin_amdgcn_s_sleep(SLP);
        (void)__hip_atomic_load(p, __ATOMIC_ACQUIRE, __HIP_MEMORY_SCOPE_AGENT); // inv once
    }
    __syncthreads();
}
// call AFTER __syncthreads (vmcnt drained at barrier): one thread fences + releases
__device__ __forceinline__ void block_release(int* p) {
    if (threadIdx.x == 0) {
        __threadfence();
        __hip_atomic_fetch_add(p, 1, __ATOMIC_RELEASE, __HIP_MEMORY_SCOPE_AGENT);
    }
}

// ---- LDS overlay: recur (~99.3 KB) / worker (36.9 KB). >=82KB forces 1 block/CU (160KB pool). ----
struct SmemRecur {
    int4 wlds[4][6][256];   // [gate][chunk][unit], k in [208,256): 98,304 B
    f16  hbuf[2][256];      // 1,024 B
};
struct SmemWorker {
    f16 As[128][72];
    f16 Bs[128][72];
};
union PipeSmem { SmemRecur r; SmemWorker w; };

// ---------------- dtype detection ----------------
__global__ void k_detect(const unsigned short* __restrict__ e, int* __restrict__ flag) {
    __shared__ int cnt;
    if (threadIdx.x == 0) cnt = 0;
    __syncthreads();
    unsigned short v = e[threadIdx.x];
    int ex = (v >> 7) & 0xFF;
    if (ex >= 100 && ex < 127) atomicAdd(&cnt, 1);
    __syncthreads();
    if (threadIdx.x == 0) *flag = (cnt >= 200) ? 1 : 0;   // 1 = bf16, 0 = fp32
}

// ---------------- flag zero ----------------
__global__ void k_zero(int* __restrict__ flags) { flags[threadIdx.x] = 0; }

// ---------------- embedding ----------------
__global__ void k_embed(const int* __restrict__ rt, const int* __restrict__ re, const int* __restrict__ rm,
                        const void* __restrict__ Ert, const void* __restrict__ Ere,
                        const void* __restrict__ Erm, f16* __restrict__ emb,
                        const int* __restrict__ flag) {
    const int isbf = *flag;
    int gid = blockIdx.x * 256 + threadIdx.x;      // < 16384*512
    int bs = gid >> 9, h = gid & 511;
    float v = ldf(Ert, (long)rt[bs] * H_ + h, isbf)
            + ldf(Ere, (long)re[bs] * H_ + h, isbf)
            + ldf(Erm, (long)rm[bs] * H_ + h, isbf);
    emb[gid] = (f16)v;
}

// ---------------- weight conversion -> f16, bias = bih+bhh (f32) ----------------
__global__ void k_wconv(const void* __restrict__ Wih, const void* __restrict__ Whh,
                        const void* __restrict__ bih, const void* __restrict__ bhh,
                        f16* __restrict__ wih, f16* __restrict__ whh, float* __restrict__ bias,
                        const int* __restrict__ flag) {
    const int isbf = *flag;
    int gid = blockIdx.x * 256 + threadIdx.x;      // < 2,097,152
    wih[gid] = (f16)ldf(Wih, gid, isbf);
    if (gid < 1048576) whh[gid] = (f16)ldf(Whh, gid, isbf);
    if (gid < 4096)    bias[gid] = ldf(bih, gid, isbf) + ldf(bhh, gid, isbf);
}

// ---------------- GEMM: C[16384][2048] = A[16384][512] * W[2048][512]^T (f16, fp32 acc) ----------------
__global__ __launch_bounds__(256) void k_gemm(const f16* __restrict__ A, const f16* __restrict__ Bm,
                                              f16* __restrict__ C) {
    const int bm = blockIdx.x & 127;
    const int bn = blockIdx.x >> 7;
    const int tid = threadIdx.x;
    const int lane = tid & 63, wave = tid >> 6;
    const int wm = wave & 1, wn = wave >> 1;
    __shared__ __align__(16) f16 As[128][72];
    __shared__ __align__(16) f16 Bs[128][72];
    f32x4 acc[4][4];
#pragma unroll
    for (int i = 0; i < 4; ++i)
#pragma unroll
        for (int jj = 0; jj < 4; ++jj) acc[i][jj] = (f32x4){0.f, 0.f, 0.f, 0.f};
    const long abase = (long)bm * 128 * K0;
    const long bbase = (long)bn * 128 * K0;
    for (int kt = 0; kt < K0; kt += 64) {
#pragma unroll
        for (int p = 0; p < 4; ++p) {
            int r = p * 32 + (tid >> 3), s = tid & 7;
            *(int4*)&As[r][s * 8] = *(const int4*)(A  + abase + (long)r * K0 + kt + s * 8);
            *(int4*)&Bs[r][s * 8] = *(const int4*)(Bm + bbase + (long)r * K0 + kt + s * 8);
        }
        __syncthreads();
        const int quad = lane >> 4, l15 = lane & 15;
#pragma unroll
        for (int kc = 0; kc < 64; kc += 32) {
            f16x8 af[4], bf[4];
#pragma unroll
            for (int mt = 0; mt < 4; ++mt) af[mt] = *(const f16x8*)&As[wm * 64 + mt * 16 + l15][kc + quad * 8];
#pragma unroll
            for (int nt = 0; nt < 4; ++nt) bf[nt] = *(const f16x8*)&Bs[wn * 64 + nt * 16 + l15][kc + quad * 8];
#pragma unroll
            for (int mt = 0; mt < 4; ++mt)
#pragma unroll
                for (int nt = 0; nt < 4; ++nt)
                    acc[mt][nt] = __builtin_amdgcn_mfma_f32_16x16x32_f16(af[mt], bf[nt], acc[mt][nt], 0, 0, 0);
        }
        __syncthreads();
    }
    const int quad = lane >> 4, l15 = lane & 15;
#pragma unroll
    for (int mt = 0; mt < 4; ++mt)
#pragma unroll
        for (int nt = 0; nt < 4; ++nt)
#pragma unroll
            for (int r = 0; r < 4; ++r) {
                int row = bm * 128 + wm * 64 + mt * 16 + quad * 4 + r;
                int col = bn * 128 + wn * 64 + nt * 16 + l15;
                C[(long)row * 2048 + col] = (f16)acc[mt][nt][r];
            }
}

// ---------------- recurrence: 256 threads, thread j = unit j, ALL 4 gates local ----------------
// Weights per thread: 2KB = 128 int4. k<208 (104 int4) in registers (AGPR-spilled, round-5-proven),
// k in [208,256) (24 int4) in LDS. h read as 32 broadcast int4/step. One barrier/step.
__device__ void recur_body(PipeSmem* SM,
    const f16* __restrict__ xp, const f16* __restrict__ whh, const float* __restrict__ bias,
    const void* __restrict__ h0, const void* __restrict__ c0,
    f16* __restrict__ yf16, void* __restrict__ yout,
    int layer, int isbf, int q, int d, int* rel, int* acq) {

    const int j = threadIdx.x;                      // unit 0..255
    const int ld = layer * 2 + d;
    SmemRecur& S = SM->r;

    // stage weights: 26 int4 per gate into regs, 6 per gate into LDS
    int4 wreg[4][26];
#pragma unroll
    for (int tt = 0; tt < 4; ++tt) {
        const int4* r = (const int4*)(whh + ((long)ld * NG + tt * 256 + j) * 256);
#pragma unroll
        for (int c = 0; c < 26; ++c) wreg[tt][c] = r[c];
#pragma unroll
        for (int c = 0; c < 6; ++c)  S.wlds[tt][c][j] = r[26 + c];
    }
    float bs0 = bias[ld * NG +   0 + j];
    float bs1 = bias[ld * NG + 256 + j];
    float bs2 = bias[ld * NG + 512 + j];
    float bs3 = bias[ld * NG + 768 + j];

    float cst = 0.f, hv = 0.f;
    if (q == 0) {                                   // chain 0 starts from h0/c0; others from reset
        cst = ldf(c0, ld * 256 + j, isbf);
        hv  = ldf(h0, ld * 256 + j, isbf);
    }
    S.hbuf[0][j] = (f16)hv;
    __syncthreads();

    int cur = 0;
    for (int i = 0; i < 32; ++i) {
        const int b = q * 32 + i;
        if (acq) block_wait_ge<2>(&acq[b], 16);     // layer-1: all 16 xp tiles of sample b ready
        for (int ti = 0; ti < 128; ++ti) {
            const int t = d ? (127 - ti) : ti;
            const f16* xr = xp + ((long)b * 128 + t) * 2048 + d * NG + j;
            f16 p0 = xr[0];                         // gate preact inputs; latency hidden
            f16 p1 = xr[256];                       // under the ~2000-cycle dot loop (vmcnt)
            f16 p2 = xr[512];
            f16 p3 = xr[768];

            float a0 = bs0, a1 = bs1, a2 = bs2, a3 = bs3;
            const int4* hp = (const int4*)S.hbuf[cur];
            // k < 208: register weights (broadcast h)
#pragma unroll
            for (int c = 0; c < 26; ++c) {
                int4 hh = hp[c];
                int4 w0 = wreg[0][c], w1 = wreg[1][c], w2 = wreg[2][c], w3 = wreg[3][c];
                a0 = dot2f(w0.x, hh.x, a0); a0 = dot2f(w0.y, hh.y, a0);
                a0 = dot2f(w0.z, hh.z, a0); a0 = dot2f(w0.w, hh.w, a0);
                a1 = dot2f(w1.x, hh.x, a1); a1 = dot2f(w1.y, hh.y, a1);
                a1 = dot2f(w1.z, hh.z, a1); a1 = dot2f(w1.w, hh.w, a1);
                a2 = dot2f(w2.x, hh.x, a2); a2 = dot2f(w2.y, hh.y, a2);
                a2 = dot2f(w2.z, hh.z, a2); a2 = dot2f(w2.w, hh.w, a2);
                a3 = dot2f(w3.x, hh.x, a3); a3 = dot2f(w3.y, hh.y, a3);
                a3 = dot2f(w3.z, hh.z, a3); a3 = dot2f(w3.w, hh.w, a3);
            }
            // k in [208,256): LDS weights (b128 stride-16, conflict-free)
#pragma unroll
            for (int c = 0; c < 6; ++c) {
                int4 hh = hp[26 + c];
                int4 w0 = S.wlds[0][c][j], w1 = S.wlds[1][c][j];
                int4 w2 = S.wlds[2][c][j], w3 = S.wlds[3][c][j];
                a0 = dot2f(w0.x, hh.x, a0); a0 = dot2f(w0.y, hh.y, a0);
                a0 = dot2f(w0.z, hh.z, a0); a0 = dot2f(w0.w, hh.w, a0);
                a1 = dot2f(w1.x, hh.x, a1); a1 = dot2f(w1.y, hh.y, a1);
                a1 = dot2f(w1.z, hh.z, a1); a1 = dot2f(w1.w, hh.w, a1);
                a2 = dot2f(w2.x, hh.x, a2); a2 = dot2f(w2.y, hh.y, a2);
                a2 = dot2f(w2.z, hh.z, a2); a2 = dot2f(w2.w, hh.w, a2);
                a3 = dot2f(w3.x, hh.x, a3); a3 = dot2f(w3.y, hh.y, a3);
                a3 = dot2f(w3.z, hh.z, a3); a3 = dot2f(w3.w, hh.w, a3);
            }
            a0 += (float)p0; a1 += (float)p1; a2 += (float)p2; a3 += (float)p3;

            float ig = sigmoidf_(a0);
            float fg = sigmoidf_(a1);
            float gg = tanhf_(a2);
            float og = sigmoidf_(a3);
            cst = fg * cst + ig * gg;
            float hn = og * tanhf_(cst);
            S.hbuf[cur ^ 1][j] = (f16)hn;
            long oidx = ((long)b * 128 + t) * 512 + d * 256 + j;
            if (layer == 0) {
                yf16[oidx] = (f16)hn;
            } else {
                if (isbf) ((__hip_bfloat16*)yout)[oidx] = __float2bfloat16(hn);
                else      ((float*)yout)[oidx] = hn;
            }
            cur ^= 1;
            __syncthreads();                        // hbuf[cur] ready (drains vmcnt/lgkm)
        }
        if (rel) block_release(&rel[b]);            // layer-0: publish sample b
    }
}

// ---------------- pipelined GEMM worker: one 128x128 tile of xp1, 16 tiles/sample ----------------
// item e: ii = e>>6 (sample within stream), q = (e&63)>>4, n = e&15 (col tile). Round-robin
// over streams so every stream's layer-1 is fed at T0 pace.
__device__ void worker_body(PipeSmem* SM, const f16* __restrict__ y0, const f16* __restrict__ wih1,
                            f16* __restrict__ xpb, int* flags, int wid) {
    SmemWorker& S = SM->w;
    const int tid = threadIdx.x;
    const int lane = tid & 63, wave = tid >> 6;
    const int wm = wave & 1, wn = wave >> 1;
    const int quad = lane >> 4, l15 = lane & 15;

    for (int e = wid; e < 2048; e += 32) {
        const int ii = e >> 6, rem = e & 63, q = rem >> 4, n = rem & 15;
        const int b = q * 32 + ii;
        block_wait_ge<32>(&flags[b], 2);            // both dirs of layer-0 done with sample b
        const long abase = (long)b * 128 * K0;
        const long bbase = (long)n * 128 * K0;
        f32x4 acc[4][4];
#pragma unroll
        for (int a = 0; a < 4; ++a)
#pragma unroll
            for (int c = 0; c < 4; ++c) acc[a][c] = (f32x4){0.f, 0.f, 0.f, 0.f};
        for (int kt = 0; kt < K0; kt += 64) {
#pragma unroll
            for (int p = 0; p < 4; ++p) {
                int r = p * 32 + (tid >> 3), s = tid & 7;
                *(int4*)&S.As[r][s * 8] = *(const int4*)(y0   + abase + (long)r * K0 + kt + s * 8);
                *(int4*)&S.Bs[r][s * 8] = *(const int4*)(wih1 + bbase + (long)r * K0 + kt + s * 8);
            }
            __syncthreads();
#pragma unroll
            for (int kc = 0; kc < 64; kc += 32) {
                f16x8 af[4], bf[4];
#pragma unroll
                for (int mt = 0; mt < 4; ++mt) af[mt] = *(const f16x8*)&S.As[wm * 64 + mt * 16 + l15][kc + quad * 8];
#pragma unroll
                for (int nt = 0; nt < 4; ++nt) bf[nt] = *(const f16x8*)&S.Bs[wn * 64 + nt * 16 + l15][kc + quad * 8];
#pragma unroll
                for (int mt = 0; mt < 4; ++mt)
#pragma unroll
                    for (int nt = 0; nt < 4; ++nt)
                        acc[mt][nt] = __builtin_amdgcn_mfma_f32_16x16x32_f16(af[mt], bf[nt], acc[mt][nt], 0, 0, 0);
            }
            __syncthreads();
        }
#pragma unroll
        for (int mt = 0; mt < 4; ++mt)
#pragma unroll
            for (int nt = 0; nt < 4; ++nt)
#pragma unroll
                for (int r = 0; r < 4; ++r) {
                    int row = b * 128 + wm * 64 + mt * 16 + quad * 4 + r;
                    int col = n * 128 + wn * 64 + nt * 16 + l15;
                    xpb[(long)row * 2048 + col] = (f16)acc[mt][nt][r];
                }
        __syncthreads();                            // stores drained at barrier
        block_release(&flags[128 + b]);             // tile done -> flag1[b] += 1 (target 16)
    }
}

// ---------------- fused pipeline kernel ----------------
__global__ __launch_bounds__(256, 1) void k_pipe(
    f16* __restrict__ xpb, const f16* __restrict__ whh, const float* __restrict__ bias,
    const void* __restrict__ h0, const void* __restrict__ c0,
    f16* __restrict__ y0, void* __restrict__ yout, const f16* __restrict__ wih1,
    int* __restrict__ flags, const int* __restrict__ flag) {
    __shared__ __align__(16) PipeSmem SM;
    const int blk = blockIdx.x;
    if (blk < 8) {
        recur_body(&SM, xpb, whh, bias, h0, c0, y0, yout, 0, *flag, blk >> 1, blk & 1, flags, nullptr);
    } else if (blk < 40) {
        worker_body(&SM, y0, wih1, xpb, flags, blk - 8);
    } else {
        const int r = blk - 40;
        recur_body(&SM, xpb, whh, bias, h0, c0, y0, yout, 1, *flag, r >> 1, r & 1, nullptr, flags + 128);
    }
}

// ---------------- fallback: standalone recurrence ----------------
__global__ __launch_bounds__(256, 1) void k_recur_solo(
    const f16* __restrict__ xp, const f16* __restrict__ whh, const float* __restrict__ bias,
    const void* __restrict__ h0, const void* __restrict__ c0,
    f16* __restrict__ yf16, void* __restrict__ yout, int layer, const int* __restrict__ flag) {
    __shared__ __align__(16) PipeSmem SM;
    recur_body(&SM, xp, whh, bias, h0, c0, yf16, yout, layer, *flag,
               blockIdx.x >> 1, blockIdx.x & 1, nullptr, nullptr);
}

// ---------------- max over batch axis ----------------
__global__ void k_maxpool(const void* __restrict__ bil, void* __restrict__ outbase,
                          const int* __restrict__ flag) {
    const int isbf = *flag;
    int gid = blockIdx.x * 256 + threadIdx.x;      // s*512+h, < 65536
    float m = -1e30f;
    for (int b = 0; b < 128; ++b)
        m = fmaxf(m, ldf(bil, (long)b * 65536 + gid, isbf));
    long o = (long)M_ * H_ + gid;
    if (isbf) ((__hip_bfloat16*)outbase)[o] = __float2bfloat16(m);
    else      ((float*)outbase)[o] = m;
}

extern "C" void kernel_launch(void* const* d_in, const int* in_sizes, int n_in,
                              void* d_out, int out_size, void* d_ws, size_t ws_size,
                              hipStream_t stream) {
    const int* rt = (const int*)d_in[0];
    const int* re = (const int*)d_in[1];
    const int* rm = (const int*)d_in[2];
    const void* h0  = d_in[3];
    const void* c0  = d_in[4];
    const void* Ert = d_in[5];
    const void* Ere = d_in[6];
    const void* Erm = d_in[7];
    const void* Wih = d_in[8];
    const void* Whh = d_in[9];
    const void* bih = d_in[10];
    const void* bhh = d_in[11];

    if (ws_size < WS_BASE) return;
    const bool pipe = (ws_size >= WS_PIPE);

    char* ws = (char*)d_ws;
    f16*   emb  = (f16*)(ws);                      // 16,777,216 B
    f16*   wih  = (f16*)(ws + 16777216);           //  4,194,304 B  [2][2][1024][512]
    f16*   whh  = (f16*)(ws + 20971520);           //  2,097,152 B  [2][2][1024][256]
    float* bias = (float*)(ws + 23068672);         //     16,384 B  [2][2][1024]
    f16*   xpb  = (f16*)(ws + 23085056);           // 67,108,864 B  [16384][2048]
    f16*   y0   = (f16*)(ws + 90193920);           // 16,777,216 B  [16384][512]
    int*   flag = (int*)(ws + 106971136);          //          4 B
    int*   flags= (int*)(ws + 106971200);          //      1,024 B  flag0[128] + flag1[128]

    hipLaunchKernelGGL(k_detect, dim3(1),     dim3(256), 0, stream, (const unsigned short*)Ert, flag);
    hipLaunchKernelGGL(k_embed,  dim3(32768), dim3(256), 0, stream, rt, re, rm, Ert, Ere, Erm, emb, flag);
    hipLaunchKernelGGL(k_wconv,  dim3(8192),  dim3(256), 0, stream, Wih, Whh, bih, bhh, wih, whh, bias, flag);
    hipLaunchKernelGGL(k_gemm,   dim3(2048),  dim3(256), 0, stream, emb, wih, xpb);
    if (pipe) {
        hipLaunchKernelGGL(k_zero, dim3(1),   dim3(256), 0, stream, flags);
        hipLaunchKernelGGL(k_pipe, dim3(48),  dim3(256), 0, stream,
                           xpb, whh, bias, h0, c0, y0, d_out, wih + (long)2 * NG * K0, flags, flag);
    } else {
        hipLaunchKernelGGL(k_recur_solo, dim3(8), dim3(256), 0, stream, xpb, whh, bias, h0, c0, y0, d_out, 0, flag);
        hipLaunchKernelGGL(k_gemm,  dim3(2048), dim3(256), 0, stream, y0, wih + (long)2 * NG * K0, xpb);
        hipLaunchKernelGGL(k_recur_solo, dim3(8), dim3(256), 0, stream, xpb, whh, bias, h0, c0, y0, d_out, 1, flag);
    }
    hipLaunchKernelGGL(k_maxpool, dim3(256),  dim3(256), 0, stream, d_out, d_out, flag);
}